// Round 3
// baseline (711.595 us; speedup 1.0000x reference)
//
#include <hip/hip_runtime.h>
#include <hip/hip_fp16.h>
#include <math.h>

#define NND 50000
#define NE  800000
#define HID 128
#define NGR 32
#define NLAYER 4

static __device__ __forceinline__ unsigned fenc(float f){
  unsigned u = __float_as_uint(f);
  return (u & 0x80000000u) ? ~u : (u | 0x80000000u);
}
static __device__ __forceinline__ float fdec(unsigned u){
  return __uint_as_float((u & 0x80000000u) ? (u & 0x7fffffffu) : ~u);
}

// ---------------- CSR build ----------------
__global__ void k_count(const int* __restrict__ ei, int* __restrict__ cnt, int E, int N){
  int e = blockIdx.x * blockDim.x + threadIdx.x;
  if (e >= E + N) return;
  int dst = (e < E) ? ei[E + e] : (e - E);   // self-loops appended
  atomicAdd(&cnt[dst], 1);
}

__global__ __launch_bounds__(256) void k_bsum(const int* __restrict__ cnt, int* __restrict__ bsum, int n){
  int i = blockIdx.x * 256 + threadIdx.x;
  int v = (i < n) ? cnt[i] : 0;
#pragma unroll
  for (int o = 32; o; o >>= 1) v += __shfl_down(v, o);
  __shared__ int s[4];
  int lane = threadIdx.x & 63, wid = threadIdx.x >> 6;
  if (lane == 0) s[wid] = v;
  __syncthreads();
  if (threadIdx.x == 0) bsum[blockIdx.x] = s[0] + s[1] + s[2] + s[3];
}

__global__ __launch_bounds__(256) void k_scanb(int* __restrict__ bsum, int nb){
  __shared__ int ps[256];
  int t = threadIdx.x;
  int v = (t < nb) ? bsum[t] : 0;
  ps[t] = v; __syncthreads();
  for (int o = 1; o < 256; o <<= 1){
    int u = (t >= o) ? ps[t - o] : 0;
    __syncthreads();
    ps[t] += u;
    __syncthreads();
  }
  if (t < nb) bsum[t] = ps[t] - v;  // exclusive
}

__global__ __launch_bounds__(256) void k_off(const int* __restrict__ cnt, const int* __restrict__ bsum,
                                             int* __restrict__ off, int n){
  __shared__ int ps[256];
  int t = threadIdx.x;
  int i = blockIdx.x * 256 + t;
  int v = (i < n) ? cnt[i] : 0;
  ps[t] = v; __syncthreads();
  for (int o = 1; o < 256; o <<= 1){
    int u = (t >= o) ? ps[t - o] : 0;
    __syncthreads();
    ps[t] += u;
    __syncthreads();
  }
  int excl = ps[t] - v + bsum[blockIdx.x];
  if (i < n) off[i] = excl;
  if (i == n - 1) off[n] = excl + v;
}

__global__ void k_fill(const int* __restrict__ ei, const int* __restrict__ off,
                       int* __restrict__ cursor, int* __restrict__ csr_src, int E, int N){
  int e = blockIdx.x * blockDim.x + threadIdx.x;
  if (e >= E + N) return;
  int src, dst;
  if (e < E){ src = ei[e]; dst = ei[E + e]; } else { src = e - E; dst = e - E; }
  int pos = off[dst] + atomicAdd(&cursor[dst], 1);
  csr_src[pos] = src;
}

// ---------------- GEMM [N,128] @ [128,128] (+bias, + fused es/ed, fp32 or fp16 out) ----------------
__global__ __launch_bounds__(256) void gemm128(const float* __restrict__ A,
    const float* __restrict__ W, const float* __restrict__ bias,
    const float* __restrict__ a_s, const float* __restrict__ a_d,
    float* __restrict__ outF, __half* __restrict__ outH,
    float* __restrict__ es, float* __restrict__ ed, int N)
{
  __shared__ float As[32][HID];
  int row0 = blockIdx.x * 32;
  int tid = threadIdx.x;
  const float4* A4 = (const float4*)A;
  float4* As4 = (float4*)(&As[0][0]);
  for (int i = tid; i < 32 * 32; i += 256) {
    int r = i >> 5;
    int gr = row0 + r;
    float4 v = make_float4(0.f, 0.f, 0.f, 0.f);
    if (gr < N) v = A4[(long)gr * 32 + (i & 31)];
    As4[i] = v;
  }
  __syncthreads();
  int tx = tid & 31, ty = tid >> 5;
  int r0 = ty * 4;
  float acc[4][4];
#pragma unroll
  for (int i = 0; i < 4; ++i)
#pragma unroll
    for (int j = 0; j < 4; ++j) acc[i][j] = 0.f;
  const float4* W4 = (const float4*)W;
#pragma unroll 4
  for (int k = 0; k < HID; ++k) {
    float4 w = W4[k * 32 + tx];
    float a0 = As[r0 + 0][k], a1 = As[r0 + 1][k], a2 = As[r0 + 2][k], a3 = As[r0 + 3][k];
    acc[0][0] += a0 * w.x; acc[0][1] += a0 * w.y; acc[0][2] += a0 * w.z; acc[0][3] += a0 * w.w;
    acc[1][0] += a1 * w.x; acc[1][1] += a1 * w.y; acc[1][2] += a1 * w.z; acc[1][3] += a1 * w.w;
    acc[2][0] += a2 * w.x; acc[2][1] += a2 * w.y; acc[2][2] += a2 * w.z; acc[2][3] += a2 * w.w;
    acc[3][0] += a3 * w.x; acc[3][1] += a3 * w.y; acc[3][2] += a3 * w.z; acc[3][3] += a3 * w.w;
  }
  float4 bb = make_float4(0.f, 0.f, 0.f, 0.f);
  if (bias) bb = ((const float4*)bias)[tx];
#pragma unroll
  for (int i = 0; i < 4; ++i) {
    int gr = row0 + r0 + i;
    if (gr < N) {
      float ox = acc[i][0] + bb.x, oy = acc[i][1] + bb.y, oz = acc[i][2] + bb.z, ow = acc[i][3] + bb.w;
      if (outF) ((float4*)outF)[(long)gr * 32 + tx] = make_float4(ox, oy, oz, ow);
      if (outH) {
        __half2 h01 = __floats2half2_rn(ox, oy);
        __half2 h23 = __floats2half2_rn(oz, ow);
        uint2 pack = make_uint2(*(unsigned*)&h01, *(unsigned*)&h23);
        ((uint2*)outH)[(long)gr * 32 + tx] = pack;
      }
    }
  }
  if (a_s) {
    float4 as4 = ((const float4*)a_s)[tx];
    float4 ad4 = ((const float4*)a_d)[tx];
#pragma unroll
    for (int i = 0; i < 4; ++i) {
      float s_ = acc[i][0] * as4.x + acc[i][1] * as4.y + acc[i][2] * as4.z + acc[i][3] * as4.w;
      float d_ = acc[i][0] * ad4.x + acc[i][1] * ad4.y + acc[i][2] * ad4.z + acc[i][3] * ad4.w;
#pragma unroll
      for (int o = 16; o; o >>= 1) { s_ += __shfl_xor(s_, o); d_ += __shfl_xor(d_, o); }
      int gr = row0 + r0 + i;
      if (tx == 0 && gr < N) { es[gr] = s_; ed[gr] = d_; }
    }
  }
}

// ---------------- fused edge softmax + aggregate + bias + LN + ELU + residual ----------------
// 4 dsts per block (one wave each), no LDS, no barriers, shuffle-only.
__global__ __launch_bounds__(256) void edge_agg(
    const __half* __restrict__ hW, const float* __restrict__ es, const float* __restrict__ ed,
    const int* __restrict__ off, const int* __restrict__ csr_src,
    const float* __restrict__ gb, const float* __restrict__ lg, const float* __restrict__ lb,
    const float* __restrict__ resid, float* __restrict__ hout, int do_elu, int N)
{
  int wid = threadIdx.x >> 6;
  int lane = threadIdx.x & 63;
  int dst = blockIdx.x * 4 + wid;
  if (dst >= N) return;
  int b = off[dst], e = off[dst + 1];
  int deg = e - b;
  float edv = ed[dst];
  const __half2* h2 = (const __half2*)hW;
  float2 acc = make_float2(0.f, 0.f);

  if (deg <= 64) {
    // single-pass softmax: one gather, all state in registers
    int s = 0; float x = -1e30f;
    if (lane < deg) {
      s = csr_src[b + lane];
      float xx = es[s] + edv;
      x = xx > 0.f ? xx : 0.2f * xx;
    }
    float m = x;
#pragma unroll
    for (int o = 32; o; o >>= 1) m = fmaxf(m, __shfl_xor(m, o));
    float p = (lane < deg) ? __expf(x - m) : 0.f;
    float z = p;
#pragma unroll
    for (int o = 32; o; o >>= 1) z += __shfl_xor(z, o);
    float a_l = p / z;
#pragma unroll 8
    for (int t = 0; t < deg; ++t) {
      float a = __shfl(a_l, t);
      int  ss = __shfl(s, t);
      __half2 hv = h2[(long)ss * 64 + lane];
      float2 f = __half22float2(hv);
      acc.x += a * f.x;
      acc.y += a * f.y;
    }
  } else {
    // generic fallback (rare): 3-pass
    float m = -1e30f;
    for (int j = b + lane; j < e; j += 64) {
      float x = es[csr_src[j]] + edv;
      x = x > 0.f ? x : 0.2f * x;
      m = fmaxf(m, x);
    }
#pragma unroll
    for (int o = 32; o; o >>= 1) m = fmaxf(m, __shfl_xor(m, o));
    float z = 0.f;
    for (int j = b + lane; j < e; j += 64) {
      float x = es[csr_src[j]] + edv;
      x = x > 0.f ? x : 0.2f * x;
      z += __expf(x - m);
    }
#pragma unroll
    for (int o = 32; o; o >>= 1) z += __shfl_xor(z, o);
    float inv_z = 1.0f / z;
    for (int c0 = b; c0 < e; c0 += 64) {
      int j = c0 + lane;
      int cnt = min(64, e - c0);
      int s = 0; float p = 0.f;
      if (j < e) {
        s = csr_src[j];
        float x = es[s] + edv;
        x = x > 0.f ? x : 0.2f * x;
        p = __expf(x - m) * inv_z;
      }
      for (int t = 0; t < cnt; ++t) {
        float a = __shfl(p, t);
        int  ss = __shfl(s, t);
        float2 f = __half22float2(h2[(long)ss * 64 + lane]);
        acc.x += a * f.x;
        acc.y += a * f.y;
      }
    }
  }

  float v0 = acc.x + gb[2 * lane];
  float v1 = acc.y + gb[2 * lane + 1];
  float s1 = v0 + v1, s2 = v0 * v0 + v1 * v1;
#pragma unroll
  for (int o = 32; o; o >>= 1) { s1 += __shfl_xor(s1, o); s2 += __shfl_xor(s2, o); }
  float mu = s1 * (1.f / 128.f);
  float var = s2 * (1.f / 128.f) - mu * mu;
  float rstd = rsqrtf(var + 1e-5f);
  float y0 = (v0 - mu) * rstd * lg[2 * lane] + lb[2 * lane];
  float y1 = (v1 - mu) * rstd * lg[2 * lane + 1] + lb[2 * lane + 1];
  if (do_elu) {
    y0 = y0 > 0.f ? y0 : expm1f(y0);
    y1 = y1 > 0.f ? y1 : expm1f(y1);
  }
  float2 r = ((const float2*)resid)[(long)dst * 64 + lane];
  ((float2*)hout)[(long)dst * 64 + lane] = make_float2(y0 + r.x, y1 + r.y);
}

// ---------------- pooling (mean + max per graph) ----------------
__global__ __launch_bounds__(128) void k_pool(const float* __restrict__ h, const int* __restrict__ batch,
    float* __restrict__ gsum, unsigned* __restrict__ gmax, int* __restrict__ gcnt, int N)
{
  int n0 = blockIdx.x * 64;
  int c = threadIdx.x;
  int cur = -1; float ls = 0.f, lm = -1e30f; int lc = 0;
  for (int i = 0; i < 64; ++i) {
    int n = n0 + i;
    if (n >= N) break;
    int g = batch[n];
    if (g != cur) {
      if (lc > 0) {
        atomicAdd(&gsum[cur * HID + c], ls);
        atomicMax(&gmax[cur * HID + c], fenc(lm));
        if (c == 0) atomicAdd(&gcnt[cur], lc);
      }
      cur = g; ls = 0.f; lm = -1e30f; lc = 0;
    }
    float v = h[(long)n * HID + c];
    ls += v; lm = fmaxf(lm, v); lc++;
  }
  if (lc > 0) {
    atomicAdd(&gsum[cur * HID + c], ls);
    atomicMax(&gmax[cur * HID + c], fenc(lm));
    if (c == 0) atomicAdd(&gcnt[cur], lc);
  }
}

// ---------------- final MLP, single block ----------------
__global__ __launch_bounds__(256) void k_mlp(const float* __restrict__ gsum,
    const unsigned* __restrict__ gmax, const int* __restrict__ gcnt,
    const float* __restrict__ W1, const float* __restrict__ b1,
    const float* __restrict__ W2, const float* __restrict__ b2,
    const float* __restrict__ W3, const float* __restrict__ b3,
    float* __restrict__ out)
{
  __shared__ float G[NGR * 256];
  __shared__ float O1[NGR * 128];
  __shared__ float O2[NGR * 64];
  int tid = threadIdx.x;
  for (int idx = tid; idx < NGR * 256; idx += 256) {
    int r = idx >> 8, c = idx & 255;
    float v;
    if (c < 128) v = gsum[r * HID + c] / fmaxf((float)gcnt[r], 1.0f);
    else v = fdec(gmax[r * HID + (c - 128)]);
    G[idx] = v;
  }
  __syncthreads();
  {
    int c = tid & 127, rg = tid >> 7;
    float acc[16];
#pragma unroll
    for (int r = 0; r < 16; ++r) acc[r] = 0.f;
    for (int k = 0; k < 256; ++k) {
      float w = W1[k * 128 + c];
#pragma unroll
      for (int r = 0; r < 16; ++r) acc[r] += G[(rg * 16 + r) * 256 + k] * w;
    }
#pragma unroll
    for (int r = 0; r < 16; ++r) {
      float v = acc[r] + b1[c];
      O1[(rg * 16 + r) * 128 + c] = v > 0.f ? v : 0.f;
    }
  }
  __syncthreads();
  {
    int c = tid & 63, rg = tid >> 6;
    float acc[8];
#pragma unroll
    for (int r = 0; r < 8; ++r) acc[r] = 0.f;
    for (int k = 0; k < 128; ++k) {
      float w = W2[k * 64 + c];
#pragma unroll
      for (int r = 0; r < 8; ++r) acc[r] += O1[(rg * 8 + r) * 128 + k] * w;
    }
#pragma unroll
    for (int r = 0; r < 8; ++r) {
      float v = acc[r] + b2[c];
      O2[(rg * 8 + r) * 64 + c] = v > 0.f ? v : 0.f;
    }
  }
  __syncthreads();
  if (tid < NGR * 4) {
    int r = tid >> 2, c = tid & 3;
    float a = 0.f;
    for (int k = 0; k < 64; ++k) a += O2[r * 64 + k] * W3[k * 4 + c];
    out[r * 4 + c] = a + b3[c];
  }
}

extern "C" void kernel_launch(void* const* d_in, const int* in_sizes, int n_in,
                              void* d_out, int out_size, void* d_ws, size_t ws_size,
                              hipStream_t stream) {
  const float* x      = (const float*)d_in[0];
  const int*   ei     = (const int*)d_in[1];
  const int*   batch  = (const int*)d_in[2];
  const float* Ws     = (const float*)d_in[3];
  const float* a_src  = (const float*)d_in[4];
  const float* a_dst  = (const float*)d_in[5];
  const float* gat_b  = (const float*)d_in[6];
  const float* ln_g   = (const float*)d_in[7];
  const float* ln_b   = (const float*)d_in[8];
  const float* skip_W = (const float*)d_in[9];
  const float* skip_b = (const float*)d_in[10];
  const float* W1     = (const float*)d_in[11];
  const float* b1     = (const float*)d_in[12];
  const float* W2     = (const float*)d_in[13];
  const float* b2     = (const float*)d_in[14];
  const float* W3     = (const float*)d_in[15];
  const float* b3     = (const float*)d_in[16];
  float* out = (float*)d_out;

  const int N = NND, E = NE;
  const int NB = (N + 255) / 256;

  char* p = (char*)d_ws;
  auto alloc = [&](size_t bytes) -> void* {
    void* r = (void*)p;
    p += (bytes + 255) & ~(size_t)255;
    return r;
  };
  float*  skip  = (float*)alloc(sizeof(float) * (size_t)N * HID);
  float*  hcur  = (float*)alloc(sizeof(float) * (size_t)N * HID);
  __half* hW    = (__half*)alloc(sizeof(__half) * (size_t)N * HID);
  float*  es    = (float*)alloc(sizeof(float) * N);
  float*  ed    = (float*)alloc(sizeof(float) * N);
  int*    cnt   = (int*)alloc(sizeof(int) * N);
  int*    off   = (int*)alloc(sizeof(int) * (N + 1));
  int*    csr   = (int*)alloc(sizeof(int) * (E + N));
  int*    bsum  = (int*)alloc(sizeof(int) * NB);
  char*   zbeg  = p;
  float*  gsum  = (float*)alloc(sizeof(float) * NGR * HID);
  unsigned* gmax = (unsigned*)alloc(sizeof(unsigned) * NGR * HID);
  int*    gcnt  = (int*)alloc(sizeof(int) * NGR);
  size_t zlen = (size_t)(p - zbeg);

  // ---- CSR build ----
  hipMemsetAsync(cnt, 0, sizeof(int) * N, stream);
  int tot = E + N;
  k_count<<<(tot + 255) / 256, 256, 0, stream>>>(ei, cnt, E, N);
  k_bsum<<<NB, 256, 0, stream>>>(cnt, bsum, N);
  k_scanb<<<1, 256, 0, stream>>>(bsum, NB);
  k_off<<<NB, 256, 0, stream>>>(cnt, bsum, off, N);
  hipMemsetAsync(cnt, 0, sizeof(int) * N, stream);
  k_fill<<<(tot + 255) / 256, 256, 0, stream>>>(ei, off, cnt, csr, E, N);

  // ---- skip projection (fp32 out) ----
  int gblocks = (N + 31) / 32;
  gemm128<<<gblocks, 256, 0, stream>>>(x, skip_W, skip_b, nullptr, nullptr,
                                       skip, nullptr, nullptr, nullptr, N);

  // ---- layers ----
  for (int l = 0; l < NLAYER; ++l) {
    const float* input = (l == 0) ? x : hcur;
    const float* resid = (l == 0) ? skip : hcur;
    gemm128<<<gblocks, 256, 0, stream>>>(input, Ws + (size_t)l * HID * HID, nullptr,
                                         a_src + l * HID, a_dst + l * HID,
                                         nullptr, hW, es, ed, N);
    edge_agg<<<(N + 3) / 4, 256, 0, stream>>>(hW, es, ed, off, csr,
                                   gat_b + l * HID, ln_g + l * HID, ln_b + l * HID,
                                   resid, hcur, (l < NLAYER - 1) ? 1 : 0, N);
  }

  // ---- pooling + MLP ----
  hipMemsetAsync(zbeg, 0, zlen, stream);
  k_pool<<<(N + 63) / 64, 128, 0, stream>>>(hcur, batch, gsum, gmax, gcnt, N);
  k_mlp<<<1, 256, 0, stream>>>(gsum, gmax, gcnt, W1, b1, W2, b2, W3, b3, out);
}

// Round 4
// 619.697 us; speedup vs baseline: 1.1483x; 1.1483x over previous
//
#include <hip/hip_runtime.h>
#include <hip/hip_fp16.h>
#include <math.h>

#define NND 50000
#define NE  800000
#define HID 128
#define NGR 32
#define NLAYER 4

static __device__ __forceinline__ unsigned fenc(float f){
  unsigned u = __float_as_uint(f);
  return (u & 0x80000000u) ? ~u : (u | 0x80000000u);
}
static __device__ __forceinline__ float fdec(unsigned u){
  return __uint_as_float((u & 0x80000000u) ? (u & 0x7fffffffu) : ~u);
}

// ---------------- CSR build ----------------
__global__ __launch_bounds__(256) void k_count(const int* __restrict__ ei, int* __restrict__ cnt, int E, int N){
  int e = blockIdx.x * blockDim.x + threadIdx.x;
  if (e >= E + N) return;
  int dst = (e < E) ? ei[E + e] : (e - E);   // self-loops appended
  atomicAdd(&cnt[dst], 1);
}

__global__ __launch_bounds__(256) void k_bsum(const int* __restrict__ cnt, int* __restrict__ bsum, int n){
  int i = blockIdx.x * 256 + threadIdx.x;
  int v = (i < n) ? cnt[i] : 0;
#pragma unroll
  for (int o = 32; o; o >>= 1) v += __shfl_down(v, o);
  __shared__ int s[4];
  int lane = threadIdx.x & 63, wid = threadIdx.x >> 6;
  if (lane == 0) s[wid] = v;
  __syncthreads();
  if (threadIdx.x == 0) bsum[blockIdx.x] = s[0] + s[1] + s[2] + s[3];
}

__global__ __launch_bounds__(256) void k_scanb(int* __restrict__ bsum, int nb){
  __shared__ int ps[256];
  int t = threadIdx.x;
  int v = (t < nb) ? bsum[t] : 0;
  ps[t] = v; __syncthreads();
  for (int o = 1; o < 256; o <<= 1){
    int u = (t >= o) ? ps[t - o] : 0;
    __syncthreads();
    ps[t] += u;
    __syncthreads();
  }
  if (t < nb) bsum[t] = ps[t] - v;  // exclusive
}

__global__ __launch_bounds__(256) void k_off(const int* __restrict__ cnt, const int* __restrict__ bsum,
                                             int* __restrict__ off, int n){
  __shared__ int ps[256];
  int t = threadIdx.x;
  int i = blockIdx.x * 256 + t;
  int v = (i < n) ? cnt[i] : 0;
  ps[t] = v; __syncthreads();
  for (int o = 1; o < 256; o <<= 1){
    int u = (t >= o) ? ps[t - o] : 0;
    __syncthreads();
    ps[t] += u;
    __syncthreads();
  }
  int excl = ps[t] - v + bsum[blockIdx.x];
  if (i < n) off[i] = excl;
  if (i == n - 1) off[n] = excl + v;
}

__global__ __launch_bounds__(256) void k_fill(const int* __restrict__ ei, const int* __restrict__ off,
                       int* __restrict__ cursor, int* __restrict__ csr_src, int E, int N){
  int e = blockIdx.x * blockDim.x + threadIdx.x;
  if (e >= E + N) return;
  int src, dst;
  if (e < E){ src = ei[e]; dst = ei[E + e]; } else { src = e - E; dst = e - E; }
  int pos = off[dst] + atomicAdd(&cursor[dst], 1);
  csr_src[pos] = src;
}

// ---------------- GEMM [N,128] @ [128,128] (+bias, + fused es/ed, fp32 or fp16 out) ----------------
__global__ __launch_bounds__(256) void gemm128(const float* __restrict__ A,
    const float* __restrict__ W, const float* __restrict__ bias,
    const float* __restrict__ a_s, const float* __restrict__ a_d,
    float* __restrict__ outF, __half* __restrict__ outH,
    float* __restrict__ es, float* __restrict__ ed, int N)
{
  __shared__ float As[32][HID];
  int row0 = blockIdx.x * 32;
  int tid = threadIdx.x;
  const float4* A4 = (const float4*)A;
  float4* As4 = (float4*)(&As[0][0]);
  for (int i = tid; i < 32 * 32; i += 256) {
    int r = i >> 5;
    int gr = row0 + r;
    float4 v = make_float4(0.f, 0.f, 0.f, 0.f);
    if (gr < N) v = A4[(long)gr * 32 + (i & 31)];
    As4[i] = v;
  }
  __syncthreads();
  int tx = tid & 31, ty = tid >> 5;
  int r0 = ty * 4;
  float acc[4][4];
#pragma unroll
  for (int i = 0; i < 4; ++i)
#pragma unroll
    for (int j = 0; j < 4; ++j) acc[i][j] = 0.f;
  const float4* W4 = (const float4*)W;
#pragma unroll 4
  for (int k = 0; k < HID; ++k) {
    float4 w = W4[k * 32 + tx];
    float a0 = As[r0 + 0][k], a1 = As[r0 + 1][k], a2 = As[r0 + 2][k], a3 = As[r0 + 3][k];
    acc[0][0] += a0 * w.x; acc[0][1] += a0 * w.y; acc[0][2] += a0 * w.z; acc[0][3] += a0 * w.w;
    acc[1][0] += a1 * w.x; acc[1][1] += a1 * w.y; acc[1][2] += a1 * w.z; acc[1][3] += a1 * w.w;
    acc[2][0] += a2 * w.x; acc[2][1] += a2 * w.y; acc[2][2] += a2 * w.z; acc[2][3] += a2 * w.w;
    acc[3][0] += a3 * w.x; acc[3][1] += a3 * w.y; acc[3][2] += a3 * w.z; acc[3][3] += a3 * w.w;
  }
  float4 bb = make_float4(0.f, 0.f, 0.f, 0.f);
  if (bias) bb = ((const float4*)bias)[tx];
#pragma unroll
  for (int i = 0; i < 4; ++i) {
    int gr = row0 + r0 + i;
    if (gr < N) {
      float ox = acc[i][0] + bb.x, oy = acc[i][1] + bb.y, oz = acc[i][2] + bb.z, ow = acc[i][3] + bb.w;
      if (outF) ((float4*)outF)[(long)gr * 32 + tx] = make_float4(ox, oy, oz, ow);
      if (outH) {
        __half2 h01 = __floats2half2_rn(ox, oy);
        __half2 h23 = __floats2half2_rn(oz, ow);
        uint2 pack = make_uint2(*(unsigned*)&h01, *(unsigned*)&h23);
        ((uint2*)outH)[(long)gr * 32 + tx] = pack;
      }
    }
  }
  if (a_s) {
    float4 as4 = ((const float4*)a_s)[tx];
    float4 ad4 = ((const float4*)a_d)[tx];
#pragma unroll
    for (int i = 0; i < 4; ++i) {
      float s_ = acc[i][0] * as4.x + acc[i][1] * as4.y + acc[i][2] * as4.z + acc[i][3] * as4.w;
      float d_ = acc[i][0] * ad4.x + acc[i][1] * ad4.y + acc[i][2] * ad4.z + acc[i][3] * ad4.w;
#pragma unroll
      for (int o = 16; o; o >>= 1) { s_ += __shfl_xor(s_, o); d_ += __shfl_xor(d_, o); }
      int gr = row0 + r0 + i;
      if (tx == 0 && gr < N) { es[gr] = s_; ed[gr] = d_; }
    }
  }
}

// ---------------- fused edge softmax + aggregate + bias + LN + ELU + residual ----------------
// 4 dsts per block (one wave each). Within a wave: 4 sub-groups of 16 lanes each
// process 4 edges concurrently (16 lanes x 8 channels = 128 ch, dwordx4 loads).
__global__ __launch_bounds__(256) void edge_agg(
    const __half* __restrict__ hW, const float* __restrict__ es, const float* __restrict__ ed,
    const int* __restrict__ off, const int* __restrict__ csr_src,
    const float* __restrict__ gb, const float* __restrict__ lg, const float* __restrict__ lb,
    const float* __restrict__ resid, float* __restrict__ hout, int do_elu, int N)
{
  int wid = threadIdx.x >> 6;
  int lane = threadIdx.x & 63;
  int sub = lane >> 4;        // edge-subgroup 0..3
  int sl  = lane & 15;        // channels [sl*8, sl*8+8)
  int dst = blockIdx.x * 4 + wid;
  if (dst >= N) return;
  int b = off[dst], e = off[dst + 1];
  int deg = e - b;            // >= 1 (self-loop)
  float edv = ed[dst];

  float acc[8];
#pragma unroll
  for (int k = 0; k < 8; ++k) acc[k] = 0.f;
  const uint4* h4 = (const uint4*)hW;   // one row = 16 uint4

  if (deg <= 64) {
    // single-pass softmax, all state in registers
    int s = 0; float x = -1e30f;
    if (lane < deg) {
      s = csr_src[b + lane];
      float xx = es[s] + edv;
      x = xx > 0.f ? xx : 0.2f * xx;
    }
    float m = x;
#pragma unroll
    for (int o = 32; o; o >>= 1) m = fmaxf(m, __shfl_xor(m, o));
    float p = (lane < deg) ? __expf(x - m) : 0.f;
    float z = p;
#pragma unroll
    for (int o = 32; o; o >>= 1) z += __shfl_xor(z, o);
    float a_l = p / z;

    int iters = (deg + 3) >> 2;
#pragma unroll 2
    for (int i = 0; i < iters; ++i) {
      int idx = (i << 2) | sub;
      bool valid = idx < deg;
      int idxc = valid ? idx : (deg - 1);
      float a = __shfl(a_l, idxc);
      int  ss = __shfl(s,  idxc);
      a = valid ? a : 0.f;               // branchless tail: load row deg-1, weight 0
      uint4 q = h4[(long)ss * 16 + sl];
      float2 f0 = __half22float2(*(__half2*)&q.x);
      float2 f1 = __half22float2(*(__half2*)&q.y);
      float2 f2 = __half22float2(*(__half2*)&q.z);
      float2 f3 = __half22float2(*(__half2*)&q.w);
      acc[0] += a * f0.x; acc[1] += a * f0.y;
      acc[2] += a * f1.x; acc[3] += a * f1.y;
      acc[4] += a * f2.x; acc[5] += a * f2.y;
      acc[6] += a * f3.x; acc[7] += a * f3.y;
    }
  } else {
    // 3-pass fallback (rare)
    float m = -1e30f;
    for (int j = b + lane; j < e; j += 64) {
      float x = es[csr_src[j]] + edv;
      x = x > 0.f ? x : 0.2f * x;
      m = fmaxf(m, x);
    }
#pragma unroll
    for (int o = 32; o; o >>= 1) m = fmaxf(m, __shfl_xor(m, o));
    float z = 0.f;
    for (int j = b + lane; j < e; j += 64) {
      float x = es[csr_src[j]] + edv;
      x = x > 0.f ? x : 0.2f * x;
      z += __expf(x - m);
    }
#pragma unroll
    for (int o = 32; o; o >>= 1) z += __shfl_xor(z, o);
    float inv_z = 1.0f / z;
    for (int c0 = b; c0 < e; c0 += 64) {
      int j = c0 + lane;
      int cnt = min(64, e - c0);
      int s = 0; float p = 0.f;
      if (j < e) {
        s = csr_src[j];
        float x = es[s] + edv;
        x = x > 0.f ? x : 0.2f * x;
        p = __expf(x - m) * inv_z;
      }
      int iters = (cnt + 3) >> 2;
      for (int i = 0; i < iters; ++i) {
        int idx = (i << 2) | sub;
        bool valid = idx < cnt;
        int idxc = valid ? idx : (cnt - 1);
        float a = __shfl(p, idxc);
        int  ss = __shfl(s, idxc);
        a = valid ? a : 0.f;
        uint4 q = h4[(long)ss * 16 + sl];
        float2 f0 = __half22float2(*(__half2*)&q.x);
        float2 f1 = __half22float2(*(__half2*)&q.y);
        float2 f2 = __half22float2(*(__half2*)&q.z);
        float2 f3 = __half22float2(*(__half2*)&q.w);
        acc[0] += a * f0.x; acc[1] += a * f0.y;
        acc[2] += a * f1.x; acc[3] += a * f1.y;
        acc[4] += a * f2.x; acc[5] += a * f2.y;
        acc[6] += a * f3.x; acc[7] += a * f3.y;
      }
    }
  }

  // merge subgroup partials: every lane ends with full sum for its 8 channels
#pragma unroll
  for (int k = 0; k < 8; ++k) {
    acc[k] += __shfl_xor(acc[k], 16);
    acc[k] += __shfl_xor(acc[k], 32);
  }

  // + gat bias, then LayerNorm stats over 128 ch (reduce across 16 lanes)
  float4 g0 = ((const float4*)gb)[sl * 2];
  float4 g1 = ((const float4*)gb)[sl * 2 + 1];
  float v[8];
  v[0] = acc[0] + g0.x; v[1] = acc[1] + g0.y; v[2] = acc[2] + g0.z; v[3] = acc[3] + g0.w;
  v[4] = acc[4] + g1.x; v[5] = acc[5] + g1.y; v[6] = acc[6] + g1.z; v[7] = acc[7] + g1.w;
  float s1 = 0.f, s2 = 0.f;
#pragma unroll
  for (int k = 0; k < 8; ++k) { s1 += v[k]; s2 += v[k] * v[k]; }
#pragma unroll
  for (int o = 8; o; o >>= 1) { s1 += __shfl_xor(s1, o); s2 += __shfl_xor(s2, o); }
  float mu = s1 * (1.f / 128.f);
  float var = s2 * (1.f / 128.f) - mu * mu;
  float rstd = rsqrtf(var + 1e-5f);

  if (sub == 0) {
    float4 L0 = ((const float4*)lg)[sl * 2];
    float4 L1 = ((const float4*)lg)[sl * 2 + 1];
    float4 B0 = ((const float4*)lb)[sl * 2];
    float4 B1 = ((const float4*)lb)[sl * 2 + 1];
    float4 R0 = ((const float4*)resid)[(long)dst * 32 + sl * 2];
    float4 R1 = ((const float4*)resid)[(long)dst * 32 + sl * 2 + 1];
    float Lk[8] = {L0.x, L0.y, L0.z, L0.w, L1.x, L1.y, L1.z, L1.w};
    float Bk[8] = {B0.x, B0.y, B0.z, B0.w, B1.x, B1.y, B1.z, B1.w};
    float Rk[8] = {R0.x, R0.y, R0.z, R0.w, R1.x, R1.y, R1.z, R1.w};
    float y[8];
#pragma unroll
    for (int k = 0; k < 8; ++k) {
      float t = (v[k] - mu) * rstd * Lk[k] + Bk[k];
      if (do_elu) t = t > 0.f ? t : expm1f(t);
      y[k] = t + Rk[k];
    }
    ((float4*)hout)[(long)dst * 32 + sl * 2]     = make_float4(y[0], y[1], y[2], y[3]);
    ((float4*)hout)[(long)dst * 32 + sl * 2 + 1] = make_float4(y[4], y[5], y[6], y[7]);
  }
}

// ---------------- pooling (mean + max per graph) ----------------
__global__ __launch_bounds__(128) void k_pool(const float* __restrict__ h, const int* __restrict__ batch,
    float* __restrict__ gsum, unsigned* __restrict__ gmax, int* __restrict__ gcnt, int N)
{
  int n0 = blockIdx.x * 64;
  int c = threadIdx.x;
  int cur = -1; float ls = 0.f, lm = -1e30f; int lc = 0;
  for (int i = 0; i < 64; ++i) {
    int n = n0 + i;
    if (n >= N) break;
    int g = batch[n];
    if (g != cur) {
      if (lc > 0) {
        atomicAdd(&gsum[cur * HID + c], ls);
        atomicMax(&gmax[cur * HID + c], fenc(lm));
        if (c == 0) atomicAdd(&gcnt[cur], lc);
      }
      cur = g; ls = 0.f; lm = -1e30f; lc = 0;
    }
    float v = h[(long)n * HID + c];
    ls += v; lm = fmaxf(lm, v); lc++;
  }
  if (lc > 0) {
    atomicAdd(&gsum[cur * HID + c], ls);
    atomicMax(&gmax[cur * HID + c], fenc(lm));
    if (c == 0) atomicAdd(&gcnt[cur], lc);
  }
}

// ---------------- final MLP, single block ----------------
__global__ __launch_bounds__(256) void k_mlp(const float* __restrict__ gsum,
    const unsigned* __restrict__ gmax, const int* __restrict__ gcnt,
    const float* __restrict__ W1, const float* __restrict__ b1,
    const float* __restrict__ W2, const float* __restrict__ b2,
    const float* __restrict__ W3, const float* __restrict__ b3,
    float* __restrict__ out)
{
  __shared__ float G[NGR * 256];
  __shared__ float O1[NGR * 128];
  __shared__ float O2[NGR * 64];
  int tid = threadIdx.x;
  for (int idx = tid; idx < NGR * 256; idx += 256) {
    int r = idx >> 8, c = idx & 255;
    float v;
    if (c < 128) v = gsum[r * HID + c] / fmaxf((float)gcnt[r], 1.0f);
    else v = fdec(gmax[r * HID + (c - 128)]);
    G[idx] = v;
  }
  __syncthreads();
  {
    int c = tid & 127, rg = tid >> 7;
    float acc[16];
#pragma unroll
    for (int r = 0; r < 16; ++r) acc[r] = 0.f;
    for (int k = 0; k < 256; ++k) {
      float w = W1[k * 128 + c];
#pragma unroll
      for (int r = 0; r < 16; ++r) acc[r] += G[(rg * 16 + r) * 256 + k] * w;
    }
#pragma unroll
    for (int r = 0; r < 16; ++r) {
      float v = acc[r] + b1[c];
      O1[(rg * 16 + r) * 128 + c] = v > 0.f ? v : 0.f;
    }
  }
  __syncthreads();
  {
    int c = tid & 63, rg = tid >> 6;
    float acc[8];
#pragma unroll
    for (int r = 0; r < 8; ++r) acc[r] = 0.f;
    for (int k = 0; k < 128; ++k) {
      float w = W2[k * 64 + c];
#pragma unroll
      for (int r = 0; r < 8; ++r) acc[r] += O1[(rg * 8 + r) * 128 + k] * w;
    }
#pragma unroll
    for (int r = 0; r < 8; ++r) {
      float v = acc[r] + b2[c];
      O2[(rg * 8 + r) * 64 + c] = v > 0.f ? v : 0.f;
    }
  }
  __syncthreads();
  if (tid < NGR * 4) {
    int r = tid >> 2, c = tid & 3;
    float a = 0.f;
    for (int k = 0; k < 64; ++k) a += O2[r * 64 + k] * W3[k * 4 + c];
    out[r * 4 + c] = a + b3[c];
  }
}

extern "C" void kernel_launch(void* const* d_in, const int* in_sizes, int n_in,
                              void* d_out, int out_size, void* d_ws, size_t ws_size,
                              hipStream_t stream) {
  const float* x      = (const float*)d_in[0];
  const int*   ei     = (const int*)d_in[1];
  const int*   batch  = (const int*)d_in[2];
  const float* Ws     = (const float*)d_in[3];
  const float* a_src  = (const float*)d_in[4];
  const float* a_dst  = (const float*)d_in[5];
  const float* gat_b  = (const float*)d_in[6];
  const float* ln_g   = (const float*)d_in[7];
  const float* ln_b   = (const float*)d_in[8];
  const float* skip_W = (const float*)d_in[9];
  const float* skip_b = (const float*)d_in[10];
  const float* W1     = (const float*)d_in[11];
  const float* b1     = (const float*)d_in[12];
  const float* W2     = (const float*)d_in[13];
  const float* b2     = (const float*)d_in[14];
  const float* W3     = (const float*)d_in[15];
  const float* b3     = (const float*)d_in[16];
  float* out = (float*)d_out;

  const int N = NND, E = NE;
  const int NB = (N + 255) / 256;

  char* p = (char*)d_ws;
  auto alloc = [&](size_t bytes) -> void* {
    void* r = (void*)p;
    p += (bytes + 255) & ~(size_t)255;
    return r;
  };
  float*  skip  = (float*)alloc(sizeof(float) * (size_t)N * HID);
  float*  hcur  = (float*)alloc(sizeof(float) * (size_t)N * HID);
  __half* hW    = (__half*)alloc(sizeof(__half) * (size_t)N * HID);
  float*  es    = (float*)alloc(sizeof(float) * N);
  float*  ed    = (float*)alloc(sizeof(float) * N);
  int*    cnt   = (int*)alloc(sizeof(int) * N);
  int*    off   = (int*)alloc(sizeof(int) * (N + 1));
  int*    csr   = (int*)alloc(sizeof(int) * (E + N));
  int*    bsum  = (int*)alloc(sizeof(int) * NB);
  char*   zbeg  = p;
  float*  gsum  = (float*)alloc(sizeof(float) * NGR * HID);
  unsigned* gmax = (unsigned*)alloc(sizeof(unsigned) * NGR * HID);
  int*    gcnt  = (int*)alloc(sizeof(int) * NGR);
  size_t zlen = (size_t)(p - zbeg);

  // ---- CSR build ----
  hipMemsetAsync(cnt, 0, sizeof(int) * N, stream);
  int tot = E + N;
  k_count<<<(tot + 255) / 256, 256, 0, stream>>>(ei, cnt, E, N);
  k_bsum<<<NB, 256, 0, stream>>>(cnt, bsum, N);
  k_scanb<<<1, 256, 0, stream>>>(bsum, NB);
  k_off<<<NB, 256, 0, stream>>>(cnt, bsum, off, N);
  hipMemsetAsync(cnt, 0, sizeof(int) * N, stream);
  k_fill<<<(tot + 255) / 256, 256, 0, stream>>>(ei, off, cnt, csr, E, N);

  // ---- skip projection (fp32 out) ----
  int gblocks = (N + 31) / 32;
  gemm128<<<gblocks, 256, 0, stream>>>(x, skip_W, skip_b, nullptr, nullptr,
                                       skip, nullptr, nullptr, nullptr, N);

  // ---- layers ----
  for (int l = 0; l < NLAYER; ++l) {
    const float* input = (l == 0) ? x : hcur;
    const float* resid = (l == 0) ? skip : hcur;
    gemm128<<<gblocks, 256, 0, stream>>>(input, Ws + (size_t)l * HID * HID, nullptr,
                                         a_src + l * HID, a_dst + l * HID,
                                         nullptr, hW, es, ed, N);
    edge_agg<<<(N + 3) / 4, 256, 0, stream>>>(hW, es, ed, off, csr,
                                   gat_b + l * HID, ln_g + l * HID, ln_b + l * HID,
                                   resid, hcur, (l < NLAYER - 1) ? 1 : 0, N);
  }

  // ---- pooling + MLP ----
  hipMemsetAsync(zbeg, 0, zlen, stream);
  k_pool<<<(N + 63) / 64, 128, 0, stream>>>(hcur, batch, gsum, gmax, gcnt, N);
  k_mlp<<<1, 256, 0, stream>>>(gsum, gmax, gcnt, W1, b1, W2, b2, W3, b3, out);
}

// Round 5
// 600.357 us; speedup vs baseline: 1.1853x; 1.0322x over previous
//
#include <hip/hip_runtime.h>
#include <hip/hip_fp16.h>
#include <math.h>

#define NND 50000
#define NE  800000
#define HID 128
#define NGR 32
#define NLAYER 4

static __device__ __forceinline__ unsigned fenc(float f){
  unsigned u = __float_as_uint(f);
  return (u & 0x80000000u) ? ~u : (u | 0x80000000u);
}
static __device__ __forceinline__ float fdec(unsigned u){
  return __uint_as_float((u & 0x80000000u) ? (u & 0x7fffffffu) : ~u);
}

// ---------------- CSR build ----------------
__global__ __launch_bounds__(256) void k_count(const int* __restrict__ ei, int* __restrict__ cnt, int E, int N){
  int e = blockIdx.x * blockDim.x + threadIdx.x;
  if (e >= E + N) return;
  int dst = (e < E) ? ei[E + e] : (e - E);   // self-loops appended
  atomicAdd(&cnt[dst], 1);
}

__global__ __launch_bounds__(256) void k_bsum(const int* __restrict__ cnt, int* __restrict__ bsum, int n){
  int i = blockIdx.x * 256 + threadIdx.x;
  int v = (i < n) ? cnt[i] : 0;
#pragma unroll
  for (int o = 32; o; o >>= 1) v += __shfl_down(v, o);
  __shared__ int s[4];
  int lane = threadIdx.x & 63, wid = threadIdx.x >> 6;
  if (lane == 0) s[wid] = v;
  __syncthreads();
  if (threadIdx.x == 0) bsum[blockIdx.x] = s[0] + s[1] + s[2] + s[3];
}

__global__ __launch_bounds__(256) void k_scanb(int* __restrict__ bsum, int nb){
  __shared__ int ps[256];
  int t = threadIdx.x;
  int v = (t < nb) ? bsum[t] : 0;
  ps[t] = v; __syncthreads();
  for (int o = 1; o < 256; o <<= 1){
    int u = (t >= o) ? ps[t - o] : 0;
    __syncthreads();
    ps[t] += u;
    __syncthreads();
  }
  if (t < nb) bsum[t] = ps[t] - v;  // exclusive
}

__global__ __launch_bounds__(256) void k_off(const int* __restrict__ cnt, const int* __restrict__ bsum,
                                             int* __restrict__ off, int n){
  __shared__ int ps[256];
  int t = threadIdx.x;
  int i = blockIdx.x * 256 + t;
  int v = (i < n) ? cnt[i] : 0;
  ps[t] = v; __syncthreads();
  for (int o = 1; o < 256; o <<= 1){
    int u = (t >= o) ? ps[t - o] : 0;
    __syncthreads();
    ps[t] += u;
    __syncthreads();
  }
  int excl = ps[t] - v + bsum[blockIdx.x];
  if (i < n) off[i] = excl;
  if (i == n - 1) off[n] = excl + v;
}

// cursor pre-initialized to off[] via d2d copy: 1 atomic + 1 store per edge
__global__ __launch_bounds__(256) void k_fill(const int* __restrict__ ei,
                       int* __restrict__ cursor, int* __restrict__ csr_src, int E, int N){
  int e = blockIdx.x * blockDim.x + threadIdx.x;
  if (e >= E + N) return;
  int src, dst;
  if (e < E){ src = ei[e]; dst = ei[E + e]; } else { src = e - E; dst = e - E; }
  int pos = atomicAdd(&cursor[dst], 1);
  csr_src[pos] = src;
}

// ---------------- GEMM [N,128] @ [128,128] (+bias, + fused es/ed, fp32 or fp16 out) ----------------
__global__ __launch_bounds__(256) void gemm128(const float* __restrict__ A,
    const float* __restrict__ W, const float* __restrict__ bias,
    const float* __restrict__ a_s, const float* __restrict__ a_d,
    float* __restrict__ outF, __half* __restrict__ outH,
    float* __restrict__ es, float* __restrict__ ed, int N)
{
  __shared__ float As[32][HID];
  int row0 = blockIdx.x * 32;
  int tid = threadIdx.x;
  const float4* A4 = (const float4*)A;
  float4* As4 = (float4*)(&As[0][0]);
  for (int i = tid; i < 32 * 32; i += 256) {
    int r = i >> 5;
    int gr = row0 + r;
    float4 v = make_float4(0.f, 0.f, 0.f, 0.f);
    if (gr < N) v = A4[(long)gr * 32 + (i & 31)];
    As4[i] = v;
  }
  __syncthreads();
  int tx = tid & 31, ty = tid >> 5;
  int r0 = ty * 4;
  float acc[4][4];
#pragma unroll
  for (int i = 0; i < 4; ++i)
#pragma unroll
    for (int j = 0; j < 4; ++j) acc[i][j] = 0.f;
  const float4* W4 = (const float4*)W;
#pragma unroll 4
  for (int k = 0; k < HID; ++k) {
    float4 w = W4[k * 32 + tx];
    float a0 = As[r0 + 0][k], a1 = As[r0 + 1][k], a2 = As[r0 + 2][k], a3 = As[r0 + 3][k];
    acc[0][0] += a0 * w.x; acc[0][1] += a0 * w.y; acc[0][2] += a0 * w.z; acc[0][3] += a0 * w.w;
    acc[1][0] += a1 * w.x; acc[1][1] += a1 * w.y; acc[1][2] += a1 * w.z; acc[1][3] += a1 * w.w;
    acc[2][0] += a2 * w.x; acc[2][1] += a2 * w.y; acc[2][2] += a2 * w.z; acc[2][3] += a2 * w.w;
    acc[3][0] += a3 * w.x; acc[3][1] += a3 * w.y; acc[3][2] += a3 * w.z; acc[3][3] += a3 * w.w;
  }
  float4 bb = make_float4(0.f, 0.f, 0.f, 0.f);
  if (bias) bb = ((const float4*)bias)[tx];
#pragma unroll
  for (int i = 0; i < 4; ++i) {
    int gr = row0 + r0 + i;
    if (gr < N) {
      float ox = acc[i][0] + bb.x, oy = acc[i][1] + bb.y, oz = acc[i][2] + bb.z, ow = acc[i][3] + bb.w;
      if (outF) ((float4*)outF)[(long)gr * 32 + tx] = make_float4(ox, oy, oz, ow);
      if (outH) {
        __half2 h01 = __floats2half2_rn(ox, oy);
        __half2 h23 = __floats2half2_rn(oz, ow);
        uint2 pack = make_uint2(*(unsigned*)&h01, *(unsigned*)&h23);
        ((uint2*)outH)[(long)gr * 32 + tx] = pack;
      }
    }
  }
  if (a_s) {
    float4 as4 = ((const float4*)a_s)[tx];
    float4 ad4 = ((const float4*)a_d)[tx];
#pragma unroll
    for (int i = 0; i < 4; ++i) {
      float s_ = acc[i][0] * as4.x + acc[i][1] * as4.y + acc[i][2] * as4.z + acc[i][3] * as4.w;
      float d_ = acc[i][0] * ad4.x + acc[i][1] * ad4.y + acc[i][2] * ad4.z + acc[i][3] * ad4.w;
#pragma unroll
      for (int o = 16; o; o >>= 1) { s_ += __shfl_xor(s_, o); d_ += __shfl_xor(d_, o); }
      int gr = row0 + r0 + i;
      if (tx == 0 && gr < N) { es[gr] = s_; ed[gr] = d_; }
    }
  }
}

// ---------------- fused edge softmax + aggregate + bias + LN + ELU + residual ----------------
__global__ __launch_bounds__(256) void edge_agg(
    const __half* __restrict__ hW, const float* __restrict__ es, const float* __restrict__ ed,
    const int* __restrict__ off, const int* __restrict__ csr_src,
    const float* __restrict__ gb, const float* __restrict__ lg, const float* __restrict__ lb,
    const float* __restrict__ resid, float* __restrict__ hout, int do_elu, int N)
{
  int wid = threadIdx.x >> 6;
  int lane = threadIdx.x & 63;
  int sub = lane >> 4;        // edge-subgroup 0..3
  int sl  = lane & 15;        // channels [sl*8, sl*8+8)
  int dst = blockIdx.x * 4 + wid;
  if (dst >= N) return;
  int b = off[dst], e = off[dst + 1];
  int deg = e - b;            // >= 1 (self-loop)
  float edv = ed[dst];

  float acc[8];
#pragma unroll
  for (int k = 0; k < 8; ++k) acc[k] = 0.f;
  const uint4* h4 = (const uint4*)hW;   // one row = 16 uint4

  if (deg <= 64) {
    int s = 0; float x = -1e30f;
    if (lane < deg) {
      s = csr_src[b + lane];
      float xx = es[s] + edv;
      x = xx > 0.f ? xx : 0.2f * xx;
    }
    float m = x;
#pragma unroll
    for (int o = 32; o; o >>= 1) m = fmaxf(m, __shfl_xor(m, o));
    float p = (lane < deg) ? __expf(x - m) : 0.f;
    float z = p;
#pragma unroll
    for (int o = 32; o; o >>= 1) z += __shfl_xor(z, o);
    float a_l = p / z;

    int iters = (deg + 3) >> 2;
#pragma unroll 2
    for (int i = 0; i < iters; ++i) {
      int idx = (i << 2) | sub;
      bool valid = idx < deg;
      int idxc = valid ? idx : (deg - 1);
      float a = __shfl(a_l, idxc);
      int  ss = __shfl(s,  idxc);
      a = valid ? a : 0.f;
      uint4 q = h4[(long)ss * 16 + sl];
      float2 f0 = __half22float2(*(__half2*)&q.x);
      float2 f1 = __half22float2(*(__half2*)&q.y);
      float2 f2 = __half22float2(*(__half2*)&q.z);
      float2 f3 = __half22float2(*(__half2*)&q.w);
      acc[0] += a * f0.x; acc[1] += a * f0.y;
      acc[2] += a * f1.x; acc[3] += a * f1.y;
      acc[4] += a * f2.x; acc[5] += a * f2.y;
      acc[6] += a * f3.x; acc[7] += a * f3.y;
    }
  } else {
    float m = -1e30f;
    for (int j = b + lane; j < e; j += 64) {
      float x = es[csr_src[j]] + edv;
      x = x > 0.f ? x : 0.2f * x;
      m = fmaxf(m, x);
    }
#pragma unroll
    for (int o = 32; o; o >>= 1) m = fmaxf(m, __shfl_xor(m, o));
    float z = 0.f;
    for (int j = b + lane; j < e; j += 64) {
      float x = es[csr_src[j]] + edv;
      x = x > 0.f ? x : 0.2f * x;
      z += __expf(x - m);
    }
#pragma unroll
    for (int o = 32; o; o >>= 1) z += __shfl_xor(z, o);
    float inv_z = 1.0f / z;
    for (int c0 = b; c0 < e; c0 += 64) {
      int j = c0 + lane;
      int cnt = min(64, e - c0);
      int s = 0; float p = 0.f;
      if (j < e) {
        s = csr_src[j];
        float x = es[s] + edv;
        x = x > 0.f ? x : 0.2f * x;
        p = __expf(x - m) * inv_z;
      }
      int iters = (cnt + 3) >> 2;
      for (int i = 0; i < iters; ++i) {
        int idx = (i << 2) | sub;
        bool valid = idx < cnt;
        int idxc = valid ? idx : (cnt - 1);
        float a = __shfl(p, idxc);
        int  ss = __shfl(s, idxc);
        a = valid ? a : 0.f;
        uint4 q = h4[(long)ss * 16 + sl];
        float2 f0 = __half22float2(*(__half2*)&q.x);
        float2 f1 = __half22float2(*(__half2*)&q.y);
        float2 f2 = __half22float2(*(__half2*)&q.z);
        float2 f3 = __half22float2(*(__half2*)&q.w);
        acc[0] += a * f0.x; acc[1] += a * f0.y;
        acc[2] += a * f1.x; acc[3] += a * f1.y;
        acc[4] += a * f2.x; acc[5] += a * f2.y;
        acc[6] += a * f3.x; acc[7] += a * f3.y;
      }
    }
  }

#pragma unroll
  for (int k = 0; k < 8; ++k) {
    acc[k] += __shfl_xor(acc[k], 16);
    acc[k] += __shfl_xor(acc[k], 32);
  }

  float4 g0 = ((const float4*)gb)[sl * 2];
  float4 g1 = ((const float4*)gb)[sl * 2 + 1];
  float v[8];
  v[0] = acc[0] + g0.x; v[1] = acc[1] + g0.y; v[2] = acc[2] + g0.z; v[3] = acc[3] + g0.w;
  v[4] = acc[4] + g1.x; v[5] = acc[5] + g1.y; v[6] = acc[6] + g1.z; v[7] = acc[7] + g1.w;
  float s1 = 0.f, s2 = 0.f;
#pragma unroll
  for (int k = 0; k < 8; ++k) { s1 += v[k]; s2 += v[k] * v[k]; }
#pragma unroll
  for (int o = 8; o; o >>= 1) { s1 += __shfl_xor(s1, o); s2 += __shfl_xor(s2, o); }
  float mu = s1 * (1.f / 128.f);
  float var = s2 * (1.f / 128.f) - mu * mu;
  float rstd = rsqrtf(var + 1e-5f);

  if (sub == 0) {
    float4 L0 = ((const float4*)lg)[sl * 2];
    float4 L1 = ((const float4*)lg)[sl * 2 + 1];
    float4 B0 = ((const float4*)lb)[sl * 2];
    float4 B1 = ((const float4*)lb)[sl * 2 + 1];
    float4 R0 = ((const float4*)resid)[(long)dst * 32 + sl * 2];
    float4 R1 = ((const float4*)resid)[(long)dst * 32 + sl * 2 + 1];
    float Lk[8] = {L0.x, L0.y, L0.z, L0.w, L1.x, L1.y, L1.z, L1.w};
    float Bk[8] = {B0.x, B0.y, B0.z, B0.w, B1.x, B1.y, B1.z, B1.w};
    float Rk[8] = {R0.x, R0.y, R0.z, R0.w, R1.x, R1.y, R1.z, R1.w};
    float y[8];
#pragma unroll
    for (int k = 0; k < 8; ++k) {
      float t = (v[k] - mu) * rstd * Lk[k] + Bk[k];
      if (do_elu) t = t > 0.f ? t : expm1f(t);
      y[k] = t + Rk[k];
    }
    ((float4*)hout)[(long)dst * 32 + sl * 2]     = make_float4(y[0], y[1], y[2], y[3]);
    ((float4*)hout)[(long)dst * 32 + sl * 2 + 1] = make_float4(y[4], y[5], y[6], y[7]);
  }
}

// ---------------- pooling (mean + max per graph) ----------------
__global__ __launch_bounds__(128) void k_pool(const float* __restrict__ h, const int* __restrict__ batch,
    float* __restrict__ gsum, unsigned* __restrict__ gmax, int* __restrict__ gcnt, int N)
{
  int n0 = blockIdx.x * 64;
  int c = threadIdx.x;
  int cur = -1; float ls = 0.f, lm = -1e30f; int lc = 0;
  for (int i = 0; i < 64; ++i) {
    int n = n0 + i;
    if (n >= N) break;
    int g = batch[n];
    if (g != cur) {
      if (lc > 0) {
        atomicAdd(&gsum[cur * HID + c], ls);
        atomicMax(&gmax[cur * HID + c], fenc(lm));
        if (c == 0) atomicAdd(&gcnt[cur], lc);
      }
      cur = g; ls = 0.f; lm = -1e30f; lc = 0;
    }
    float v = h[(long)n * HID + c];
    ls += v; lm = fmaxf(lm, v); lc++;
  }
  if (lc > 0) {
    atomicAdd(&gsum[cur * HID + c], ls);
    atomicMax(&gmax[cur * HID + c], fenc(lm));
    if (c == 0) atomicAdd(&gcnt[cur], lc);
  }
}

// ---------------- final MLP: one block per graph ----------------
__global__ __launch_bounds__(128) void k_mlp(const float* __restrict__ gsum,
    const unsigned* __restrict__ gmax, const int* __restrict__ gcnt,
    const float* __restrict__ W1, const float* __restrict__ b1,
    const float* __restrict__ W2, const float* __restrict__ b2,
    const float* __restrict__ W3, const float* __restrict__ b3,
    float* __restrict__ out)
{
  int g = blockIdx.x;          // graph id
  int c = threadIdx.x;         // 0..127
  __shared__ float G[256];
  __shared__ float O1[128];
  __shared__ float O2[64];
  float inv = 1.0f / fmaxf((float)gcnt[g], 1.0f);
  G[c]       = gsum[g * HID + c] * inv;
  G[128 + c] = fdec(gmax[g * HID + c]);
  __syncthreads();
  {
    float acc = 0.f;
#pragma unroll 8
    for (int k = 0; k < 256; ++k) acc += G[k] * W1[k * 128 + c];
    float v = acc + b1[c];
    O1[c] = v > 0.f ? v : 0.f;
  }
  __syncthreads();
  if (c < 64) {
    float acc = 0.f;
#pragma unroll 8
    for (int k = 0; k < 128; ++k) acc += O1[k] * W2[k * 64 + c];
    float v = acc + b2[c];
    O2[c] = v > 0.f ? v : 0.f;
  }
  __syncthreads();
  if (c < 4) {
    float acc = 0.f;
#pragma unroll 8
    for (int k = 0; k < 64; ++k) acc += O2[k] * W3[k * 4 + c];
    out[g * 4 + c] = acc + b3[c];
  }
}

extern "C" void kernel_launch(void* const* d_in, const int* in_sizes, int n_in,
                              void* d_out, int out_size, void* d_ws, size_t ws_size,
                              hipStream_t stream) {
  const float* x      = (const float*)d_in[0];
  const int*   ei     = (const int*)d_in[1];
  const int*   batch  = (const int*)d_in[2];
  const float* Ws     = (const float*)d_in[3];
  const float* a_src  = (const float*)d_in[4];
  const float* a_dst  = (const float*)d_in[5];
  const float* gat_b  = (const float*)d_in[6];
  const float* ln_g   = (const float*)d_in[7];
  const float* ln_b   = (const float*)d_in[8];
  const float* skip_W = (const float*)d_in[9];
  const float* skip_b = (const float*)d_in[10];
  const float* W1     = (const float*)d_in[11];
  const float* b1     = (const float*)d_in[12];
  const float* W2     = (const float*)d_in[13];
  const float* b2     = (const float*)d_in[14];
  const float* W3     = (const float*)d_in[15];
  const float* b3     = (const float*)d_in[16];
  float* out = (float*)d_out;

  const int N = NND, E = NE;
  const int NB = (N + 255) / 256;

  char* p = (char*)d_ws;
  auto alloc = [&](size_t bytes) -> void* {
    void* r = (void*)p;
    p += (bytes + 255) & ~(size_t)255;
    return r;
  };
  float*  skip  = (float*)alloc(sizeof(float) * (size_t)N * HID);
  float*  hcur  = (float*)alloc(sizeof(float) * (size_t)N * HID);
  __half* hW    = (__half*)alloc(sizeof(__half) * (size_t)N * HID);
  float*  es    = (float*)alloc(sizeof(float) * N);
  float*  ed    = (float*)alloc(sizeof(float) * N);
  int*    cnt   = (int*)alloc(sizeof(int) * N);
  int*    cursor= (int*)alloc(sizeof(int) * N);
  int*    off   = (int*)alloc(sizeof(int) * (N + 1));
  int*    csr   = (int*)alloc(sizeof(int) * (E + N));
  int*    bsum  = (int*)alloc(sizeof(int) * NB);
  char*   zbeg  = p;
  float*  gsum  = (float*)alloc(sizeof(float) * NGR * HID);
  unsigned* gmax = (unsigned*)alloc(sizeof(unsigned) * NGR * HID);
  int*    gcnt  = (int*)alloc(sizeof(int) * NGR);
  size_t zlen = (size_t)(p - zbeg);

  // ---- CSR build ----
  hipMemsetAsync(cnt, 0, sizeof(int) * N, stream);
  int tot = E + N;
  k_count<<<(tot + 255) / 256, 256, 0, stream>>>(ei, cnt, E, N);
  k_bsum<<<NB, 256, 0, stream>>>(cnt, bsum, N);
  k_scanb<<<1, 256, 0, stream>>>(bsum, NB);
  k_off<<<NB, 256, 0, stream>>>(cnt, bsum, off, N);
  hipMemcpyAsync(cursor, off, sizeof(int) * N, hipMemcpyDeviceToDevice, stream);
  k_fill<<<(tot + 255) / 256, 256, 0, stream>>>(ei, cursor, csr, E, N);

  // ---- skip projection (fp32 out) ----
  int gblocks = (N + 31) / 32;
  gemm128<<<gblocks, 256, 0, stream>>>(x, skip_W, skip_b, nullptr, nullptr,
                                       skip, nullptr, nullptr, nullptr, N);

  // ---- layers ----
  for (int l = 0; l < NLAYER; ++l) {
    const float* input = (l == 0) ? x : hcur;
    const float* resid = (l == 0) ? skip : hcur;
    gemm128<<<gblocks, 256, 0, stream>>>(input, Ws + (size_t)l * HID * HID, nullptr,
                                         a_src + l * HID, a_dst + l * HID,
                                         nullptr, hW, es, ed, N);
    edge_agg<<<(N + 3) / 4, 256, 0, stream>>>(hW, es, ed, off, csr,
                                   gat_b + l * HID, ln_g + l * HID, ln_b + l * HID,
                                   resid, hcur, (l < NLAYER - 1) ? 1 : 0, N);
  }

  // ---- pooling + MLP ----
  hipMemsetAsync(zbeg, 0, zlen, stream);
  k_pool<<<(N + 63) / 64, 128, 0, stream>>>(hcur, batch, gsum, gmax, gcnt, N);
  k_mlp<<<NGR, 128, 0, stream>>>(gsum, gmax, gcnt, W1, b1, W2, b2, W3, b3, out);
}

// Round 6
// 590.164 us; speedup vs baseline: 1.2058x; 1.0173x over previous
//
#include <hip/hip_runtime.h>
#include <hip/hip_fp16.h>
#include <math.h>

#define NND 50000
#define NE  800000
#define HID 128
#define NGR 32
#define NLAYER 4
#define NPL 8                      // CSR planes (≈ XCDs)
#define TOT8 (NND * NPL)           // 400000 histogram cells

static __device__ __forceinline__ unsigned fenc(float f){
  unsigned u = __float_as_uint(f);
  return (u & 0x80000000u) ? ~u : (u | 0x80000000u);
}
static __device__ __forceinline__ float fdec(unsigned u){
  return __uint_as_float((u & 0x80000000u) ? (u & 0x7fffffffu) : ~u);
}

// ---------------- CSR build: 8-plane (XCD-local) layout ----------------
// cnt8/off8/cursor8 are d-major [dst*8+plane]; csr8 positions are plane-major
// (all of plane 0's runs, then plane 1's, ...), so plane p is a contiguous
// region written (mostly) by one XCD -> full-line write combining in its L2.

__global__ __launch_bounds__(256) void k_count8(const int* __restrict__ ei, int* __restrict__ cnt8, int E, int N){
  int e = blockIdx.x * blockDim.x + threadIdx.x;
  if (e >= E + N) return;
  int dst = (e < E) ? ei[E + e] : (e - E);   // self-loops appended
  int p = blockIdx.x & 7;
  atomicAdd(&cnt8[dst * NPL + p], 1);
}

// hierarchical scan over TOT8 elements in PLANE-MAJOR order (i = p*N + d),
// reading the d-major cnt8 transposed. 2048 elems/block -> 196 blocks.
__global__ __launch_bounds__(256) void k_bsum8(const int* __restrict__ cnt8, int* __restrict__ bsum){
  int t = threadIdx.x;
  int i0 = blockIdx.x * 2048 + t * 8;
  int s = 0;
#pragma unroll
  for (int k = 0; k < 8; ++k) {
    int i = i0 + k;
    if (i < TOT8) { int p = i / NND, d = i - p * NND; s += cnt8[d * NPL + p]; }
  }
#pragma unroll
  for (int o = 32; o; o >>= 1) s += __shfl_down(s, o);
  __shared__ int sh[4];
  int lane = t & 63, wid = t >> 6;
  if (lane == 0) sh[wid] = s;
  __syncthreads();
  if (t == 0) bsum[blockIdx.x] = sh[0] + sh[1] + sh[2] + sh[3];
}

__global__ __launch_bounds__(256) void k_scanb(int* __restrict__ bsum, int nb){
  __shared__ int ps[256];
  int t = threadIdx.x;
  int v = (t < nb) ? bsum[t] : 0;
  ps[t] = v; __syncthreads();
  for (int o = 1; o < 256; o <<= 1){
    int u = (t >= o) ? ps[t - o] : 0;
    __syncthreads();
    ps[t] += u;
    __syncthreads();
  }
  if (t < nb) bsum[t] = ps[t] - v;  // exclusive
}

__global__ __launch_bounds__(256) void k_off8(const int* __restrict__ cnt8, const int* __restrict__ bsum,
                                              int* __restrict__ off8){
  __shared__ int ps[256];
  int t = threadIdx.x;
  int i0 = blockIdx.x * 2048 + t * 8;
  int v[8]; int s = 0;
#pragma unroll
  for (int k = 0; k < 8; ++k) {
    int i = i0 + k; int val = 0;
    if (i < TOT8) { int p = i / NND, d = i - p * NND; val = cnt8[d * NPL + p]; }
    v[k] = val; s += val;
  }
  ps[t] = s; __syncthreads();
  for (int o = 1; o < 256; o <<= 1){
    int u = (t >= o) ? ps[t - o] : 0;
    __syncthreads();
    ps[t] += u;
    __syncthreads();
  }
  int run = ((t ? ps[t - 1] : 0)) + bsum[blockIdx.x];
#pragma unroll
  for (int k = 0; k < 8; ++k) {
    int i = i0 + k;
    if (i < TOT8) { int p = i / NND, d = i - p * NND; off8[d * NPL + p] = run; }
    run += v[k];
  }
}

// cursor8 pre-initialized to off8 via d2d copy
__global__ __launch_bounds__(256) void k_fill8(const int* __restrict__ ei,
                       int* __restrict__ cursor8, int* __restrict__ csr8, int E, int N){
  int e = blockIdx.x * blockDim.x + threadIdx.x;
  if (e >= E + N) return;
  int src, dst;
  if (e < E){ src = ei[e]; dst = ei[E + e]; } else { src = e - E; dst = e - E; }
  int p = blockIdx.x & 7;
  int pos = atomicAdd(&cursor8[dst * NPL + p], 1);
  csr8[pos] = src;
}

// ---------------- GEMM [N,128] @ [128,128] (+bias, + fused es/ed, fp32 or fp16 out) ----------------
__global__ __launch_bounds__(256) void gemm128(const float* __restrict__ A,
    const float* __restrict__ W, const float* __restrict__ bias,
    const float* __restrict__ a_s, const float* __restrict__ a_d,
    float* __restrict__ outF, __half* __restrict__ outH,
    float* __restrict__ es, float* __restrict__ ed, int N)
{
  __shared__ float As[32][HID];
  int row0 = blockIdx.x * 32;
  int tid = threadIdx.x;
  const float4* A4 = (const float4*)A;
  float4* As4 = (float4*)(&As[0][0]);
  for (int i = tid; i < 32 * 32; i += 256) {
    int r = i >> 5;
    int gr = row0 + r;
    float4 v = make_float4(0.f, 0.f, 0.f, 0.f);
    if (gr < N) v = A4[(long)gr * 32 + (i & 31)];
    As4[i] = v;
  }
  __syncthreads();
  int tx = tid & 31, ty = tid >> 5;
  int r0 = ty * 4;
  float acc[4][4];
#pragma unroll
  for (int i = 0; i < 4; ++i)
#pragma unroll
    for (int j = 0; j < 4; ++j) acc[i][j] = 0.f;
  const float4* W4 = (const float4*)W;
#pragma unroll 4
  for (int k = 0; k < HID; ++k) {
    float4 w = W4[k * 32 + tx];
    float a0 = As[r0 + 0][k], a1 = As[r0 + 1][k], a2 = As[r0 + 2][k], a3 = As[r0 + 3][k];
    acc[0][0] += a0 * w.x; acc[0][1] += a0 * w.y; acc[0][2] += a0 * w.z; acc[0][3] += a0 * w.w;
    acc[1][0] += a1 * w.x; acc[1][1] += a1 * w.y; acc[1][2] += a1 * w.z; acc[1][3] += a1 * w.w;
    acc[2][0] += a2 * w.x; acc[2][1] += a2 * w.y; acc[2][2] += a2 * w.z; acc[2][3] += a2 * w.w;
    acc[3][0] += a3 * w.x; acc[3][1] += a3 * w.y; acc[3][2] += a3 * w.z; acc[3][3] += a3 * w.w;
  }
  float4 bb = make_float4(0.f, 0.f, 0.f, 0.f);
  if (bias) bb = ((const float4*)bias)[tx];
#pragma unroll
  for (int i = 0; i < 4; ++i) {
    int gr = row0 + r0 + i;
    if (gr < N) {
      float ox = acc[i][0] + bb.x, oy = acc[i][1] + bb.y, oz = acc[i][2] + bb.z, ow = acc[i][3] + bb.w;
      if (outF) ((float4*)outF)[(long)gr * 32 + tx] = make_float4(ox, oy, oz, ow);
      if (outH) {
        __half2 h01 = __floats2half2_rn(ox, oy);
        __half2 h23 = __floats2half2_rn(oz, ow);
        uint2 pack = make_uint2(*(unsigned*)&h01, *(unsigned*)&h23);
        ((uint2*)outH)[(long)gr * 32 + tx] = pack;
      }
    }
  }
  if (a_s) {
    float4 as4 = ((const float4*)a_s)[tx];
    float4 ad4 = ((const float4*)a_d)[tx];
#pragma unroll
    for (int i = 0; i < 4; ++i) {
      float s_ = acc[i][0] * as4.x + acc[i][1] * as4.y + acc[i][2] * as4.z + acc[i][3] * as4.w;
      float d_ = acc[i][0] * ad4.x + acc[i][1] * ad4.y + acc[i][2] * ad4.z + acc[i][3] * ad4.w;
#pragma unroll
      for (int o = 16; o; o >>= 1) { s_ += __shfl_xor(s_, o); d_ += __shfl_xor(d_, o); }
      int gr = row0 + r0 + i;
      if (tx == 0 && gr < N) { es[gr] = s_; ed[gr] = d_; }
    }
  }
}

// ---------------- fused edge softmax + aggregate + bias + LN + ELU + residual ----------------
// 4 dsts per block (one wave each); edges come from 8 CSR planes.
__global__ __launch_bounds__(256) void edge_agg(
    const __half* __restrict__ hW, const float* __restrict__ es, const float* __restrict__ ed,
    const int* __restrict__ off8, const int* __restrict__ cnt8, const int* __restrict__ csr8,
    const float* __restrict__ gb, const float* __restrict__ lg, const float* __restrict__ lb,
    const float* __restrict__ resid, float* __restrict__ hout, int do_elu, int N)
{
  int wid = threadIdx.x >> 6;
  int lane = threadIdx.x & 63;
  int sub = lane >> 4;        // edge-subgroup 0..3
  int sl  = lane & 15;        // channels [sl*8, sl*8+8)
  int dst = blockIdx.x * 4 + wid;
  if (dst >= N) return;

  // per-dst 8-plane meta (wave-uniform addresses)
  uint4 oA = ((const uint4*)(off8 + (size_t)dst * NPL))[0];
  uint4 oB = ((const uint4*)(off8 + (size_t)dst * NPL))[1];
  uint4 cA = ((const uint4*)(cnt8 + (size_t)dst * NPL))[0];
  uint4 cB = ((const uint4*)(cnt8 + (size_t)dst * NPL))[1];
  int offv[8] = {(int)oA.x,(int)oA.y,(int)oA.z,(int)oA.w,(int)oB.x,(int)oB.y,(int)oB.z,(int)oB.w};
  int cntv[8] = {(int)cA.x,(int)cA.y,(int)cA.z,(int)cA.w,(int)cB.x,(int)cB.y,(int)cB.z,(int)cB.w};
  int cum[9]; cum[0] = 0;
#pragma unroll
  for (int k = 0; k < 8; ++k) cum[k + 1] = cum[k] + cntv[k];
  int deg = cum[8];           // >= 1 (self-loop)
  float edv = ed[dst];

  float acc[8];
#pragma unroll
  for (int k = 0; k < 8; ++k) acc[k] = 0.f;
  const uint4* h4 = (const uint4*)hW;   // one row = 16 uint4

  if (deg <= 64) {
    int s = 0; float x = -1e30f;
    if (lane < deg) {
      int p = 0;
#pragma unroll
      for (int k = 1; k < 8; ++k) if (lane >= cum[k]) p = k;
      s = csr8[offv[p] + (lane - cum[p])];
      float xx = es[s] + edv;
      x = xx > 0.f ? xx : 0.2f * xx;
    }
    float m = x;
#pragma unroll
    for (int o = 32; o; o >>= 1) m = fmaxf(m, __shfl_xor(m, o));
    float p_ = (lane < deg) ? __expf(x - m) : 0.f;
    float z = p_;
#pragma unroll
    for (int o = 32; o; o >>= 1) z += __shfl_xor(z, o);
    float a_l = p_ / z;

    int iters = (deg + 3) >> 2;
#pragma unroll 2
    for (int i = 0; i < iters; ++i) {
      int idx = (i << 2) | sub;
      bool valid = idx < deg;
      int idxc = valid ? idx : (deg - 1);
      float a = __shfl(a_l, idxc);
      int  ss = __shfl(s,  idxc);
      a = valid ? a : 0.f;
      uint4 q = h4[(long)ss * 16 + sl];
      float2 f0 = __half22float2(*(__half2*)&q.x);
      float2 f1 = __half22float2(*(__half2*)&q.y);
      float2 f2 = __half22float2(*(__half2*)&q.z);
      float2 f3 = __half22float2(*(__half2*)&q.w);
      acc[0] += a * f0.x; acc[1] += a * f0.y;
      acc[2] += a * f1.x; acc[3] += a * f1.y;
      acc[4] += a * f2.x; acc[5] += a * f2.y;
      acc[6] += a * f3.x; acc[7] += a * f3.y;
    }
  } else {
    // 3-pass fallback (deg > 64; rare)
    float m = -1e30f;
    for (int j = lane; j < deg; j += 64) {
      int p = 0;
#pragma unroll
      for (int k = 1; k < 8; ++k) if (j >= cum[k]) p = k;
      float x = es[csr8[offv[p] + (j - cum[p])]] + edv;
      x = x > 0.f ? x : 0.2f * x;
      m = fmaxf(m, x);
    }
#pragma unroll
    for (int o = 32; o; o >>= 1) m = fmaxf(m, __shfl_xor(m, o));
    float z = 0.f;
    for (int j = lane; j < deg; j += 64) {
      int p = 0;
#pragma unroll
      for (int k = 1; k < 8; ++k) if (j >= cum[k]) p = k;
      float x = es[csr8[offv[p] + (j - cum[p])]] + edv;
      x = x > 0.f ? x : 0.2f * x;
      z += __expf(x - m);
    }
#pragma unroll
    for (int o = 32; o; o >>= 1) z += __shfl_xor(z, o);
    float inv_z = 1.0f / z;
    for (int c0 = 0; c0 < deg; c0 += 64) {
      int j = c0 + lane;
      int cnt = min(64, deg - c0);
      int s = 0; float p_ = 0.f;
      if (j < deg) {
        int p = 0;
#pragma unroll
        for (int k = 1; k < 8; ++k) if (j >= cum[k]) p = k;
        s = csr8[offv[p] + (j - cum[p])];
        float x = es[s] + edv;
        x = x > 0.f ? x : 0.2f * x;
        p_ = __expf(x - m) * inv_z;
      }
      int iters = (cnt + 3) >> 2;
      for (int i = 0; i < iters; ++i) {
        int idx = (i << 2) | sub;
        bool valid = idx < cnt;
        int idxc = valid ? idx : (cnt - 1);
        float a = __shfl(p_, idxc);
        int  ss = __shfl(s, idxc);
        a = valid ? a : 0.f;
        uint4 q = h4[(long)ss * 16 + sl];
        float2 f0 = __half22float2(*(__half2*)&q.x);
        float2 f1 = __half22float2(*(__half2*)&q.y);
        float2 f2 = __half22float2(*(__half2*)&q.z);
        float2 f3 = __half22float2(*(__half2*)&q.w);
        acc[0] += a * f0.x; acc[1] += a * f0.y;
        acc[2] += a * f1.x; acc[3] += a * f1.y;
        acc[4] += a * f2.x; acc[5] += a * f2.y;
        acc[6] += a * f3.x; acc[7] += a * f3.y;
      }
    }
  }

#pragma unroll
  for (int k = 0; k < 8; ++k) {
    acc[k] += __shfl_xor(acc[k], 16);
    acc[k] += __shfl_xor(acc[k], 32);
  }

  float4 g0 = ((const float4*)gb)[sl * 2];
  float4 g1 = ((const float4*)gb)[sl * 2 + 1];
  float v[8];
  v[0] = acc[0] + g0.x; v[1] = acc[1] + g0.y; v[2] = acc[2] + g0.z; v[3] = acc[3] + g0.w;
  v[4] = acc[4] + g1.x; v[5] = acc[5] + g1.y; v[6] = acc[6] + g1.z; v[7] = acc[7] + g1.w;
  float s1 = 0.f, s2 = 0.f;
#pragma unroll
  for (int k = 0; k < 8; ++k) { s1 += v[k]; s2 += v[k] * v[k]; }
#pragma unroll
  for (int o = 8; o; o >>= 1) { s1 += __shfl_xor(s1, o); s2 += __shfl_xor(s2, o); }
  float mu = s1 * (1.f / 128.f);
  float var = s2 * (1.f / 128.f) - mu * mu;
  float rstd = rsqrtf(var + 1e-5f);

  if (sub == 0) {
    float4 L0 = ((const float4*)lg)[sl * 2];
    float4 L1 = ((const float4*)lg)[sl * 2 + 1];
    float4 B0 = ((const float4*)lb)[sl * 2];
    float4 B1 = ((const float4*)lb)[sl * 2 + 1];
    float4 R0 = ((const float4*)resid)[(long)dst * 32 + sl * 2];
    float4 R1 = ((const float4*)resid)[(long)dst * 32 + sl * 2 + 1];
    float Lk[8] = {L0.x, L0.y, L0.z, L0.w, L1.x, L1.y, L1.z, L1.w};
    float Bk[8] = {B0.x, B0.y, B0.z, B0.w, B1.x, B1.y, B1.z, B1.w};
    float Rk[8] = {R0.x, R0.y, R0.z, R0.w, R1.x, R1.y, R1.z, R1.w};
    float y[8];
#pragma unroll
    for (int k = 0; k < 8; ++k) {
      float t = (v[k] - mu) * rstd * Lk[k] + Bk[k];
      if (do_elu) t = t > 0.f ? t : expm1f(t);
      y[k] = t + Rk[k];
    }
    ((float4*)hout)[(long)dst * 32 + sl * 2]     = make_float4(y[0], y[1], y[2], y[3]);
    ((float4*)hout)[(long)dst * 32 + sl * 2 + 1] = make_float4(y[4], y[5], y[6], y[7]);
  }
}

// ---------------- pooling (mean + max per graph) ----------------
__global__ __launch_bounds__(128) void k_pool(const float* __restrict__ h, const int* __restrict__ batch,
    float* __restrict__ gsum, unsigned* __restrict__ gmax, int* __restrict__ gcnt, int N)
{
  int n0 = blockIdx.x * 64;
  int c = threadIdx.x;
  int cur = -1; float ls = 0.f, lm = -1e30f; int lc = 0;
  for (int i = 0; i < 64; ++i) {
    int n = n0 + i;
    if (n >= N) break;
    int g = batch[n];
    if (g != cur) {
      if (lc > 0) {
        atomicAdd(&gsum[cur * HID + c], ls);
        atomicMax(&gmax[cur * HID + c], fenc(lm));
        if (c == 0) atomicAdd(&gcnt[cur], lc);
      }
      cur = g; ls = 0.f; lm = -1e30f; lc = 0;
    }
    float v = h[(long)n * HID + c];
    ls += v; lm = fmaxf(lm, v); lc++;
  }
  if (lc > 0) {
    atomicAdd(&gsum[cur * HID + c], ls);
    atomicMax(&gmax[cur * HID + c], fenc(lm));
    if (c == 0) atomicAdd(&gcnt[cur], lc);
  }
}

// ---------------- final MLP: one block per graph ----------------
__global__ __launch_bounds__(128) void k_mlp(const float* __restrict__ gsum,
    const unsigned* __restrict__ gmax, const int* __restrict__ gcnt,
    const float* __restrict__ W1, const float* __restrict__ b1,
    const float* __restrict__ W2, const float* __restrict__ b2,
    const float* __restrict__ W3, const float* __restrict__ b3,
    float* __restrict__ out)
{
  int g = blockIdx.x;
  int c = threadIdx.x;
  __shared__ float G[256];
  __shared__ float O1[128];
  __shared__ float O2[64];
  float inv = 1.0f / fmaxf((float)gcnt[g], 1.0f);
  G[c]       = gsum[g * HID + c] * inv;
  G[128 + c] = fdec(gmax[g * HID + c]);
  __syncthreads();
  {
    float acc = 0.f;
#pragma unroll 8
    for (int k = 0; k < 256; ++k) acc += G[k] * W1[k * 128 + c];
    float v = acc + b1[c];
    O1[c] = v > 0.f ? v : 0.f;
  }
  __syncthreads();
  if (c < 64) {
    float acc = 0.f;
#pragma unroll 8
    for (int k = 0; k < 128; ++k) acc += O1[k] * W2[k * 64 + c];
    float v = acc + b2[c];
    O2[c] = v > 0.f ? v : 0.f;
  }
  __syncthreads();
  if (c < 4) {
    float acc = 0.f;
#pragma unroll 8
    for (int k = 0; k < 64; ++k) acc += O2[k] * W3[k * 4 + c];
    out[g * 4 + c] = acc + b3[c];
  }
}

extern "C" void kernel_launch(void* const* d_in, const int* in_sizes, int n_in,
                              void* d_out, int out_size, void* d_ws, size_t ws_size,
                              hipStream_t stream) {
  const float* x      = (const float*)d_in[0];
  const int*   ei     = (const int*)d_in[1];
  const int*   batch  = (const int*)d_in[2];
  const float* Ws     = (const float*)d_in[3];
  const float* a_src  = (const float*)d_in[4];
  const float* a_dst  = (const float*)d_in[5];
  const float* gat_b  = (const float*)d_in[6];
  const float* ln_g   = (const float*)d_in[7];
  const float* ln_b   = (const float*)d_in[8];
  const float* skip_W = (const float*)d_in[9];
  const float* skip_b = (const float*)d_in[10];
  const float* W1     = (const float*)d_in[11];
  const float* b1     = (const float*)d_in[12];
  const float* W2     = (const float*)d_in[13];
  const float* b2     = (const float*)d_in[14];
  const float* W3     = (const float*)d_in[15];
  const float* b3     = (const float*)d_in[16];
  float* out = (float*)d_out;

  const int N = NND, E = NE;
  const int NB8 = (TOT8 + 2047) / 2048;   // 196 blocks for the 400K scan

  char* p = (char*)d_ws;
  auto alloc = [&](size_t bytes) -> void* {
    void* r = (void*)p;
    p += (bytes + 255) & ~(size_t)255;
    return r;
  };
  float*  skip  = (float*)alloc(sizeof(float) * (size_t)N * HID);
  float*  hcur  = (float*)alloc(sizeof(float) * (size_t)N * HID);
  __half* hW    = (__half*)alloc(sizeof(__half) * (size_t)N * HID);
  float*  es    = (float*)alloc(sizeof(float) * N);
  float*  ed    = (float*)alloc(sizeof(float) * N);
  int*    cnt8  = (int*)alloc(sizeof(int) * TOT8);
  int*    off8  = (int*)alloc(sizeof(int) * TOT8);
  int*    csr8  = (int*)alloc(sizeof(int) * (E + N));
  int*    bsum  = (int*)alloc(sizeof(int) * NB8);
  char*   zbeg  = p;
  float*  gsum  = (float*)alloc(sizeof(float) * NGR * HID);
  unsigned* gmax = (unsigned*)alloc(sizeof(unsigned) * NGR * HID);
  int*    gcnt  = (int*)alloc(sizeof(int) * NGR);
  size_t zlen = (size_t)(p - zbeg);
  // cursor8 aliases skip[]: used only before the first gemm writes skip (stream-ordered)
  int* cursor8 = (int*)skip;

  // ---- CSR build (8-plane) ----
  hipMemsetAsync(cnt8, 0, sizeof(int) * TOT8, stream);
  int tot = E + N;
  k_count8<<<(tot + 255) / 256, 256, 0, stream>>>(ei, cnt8, E, N);
  k_bsum8<<<NB8, 256, 0, stream>>>(cnt8, bsum);
  k_scanb<<<1, 256, 0, stream>>>(bsum, NB8);
  k_off8<<<NB8, 256, 0, stream>>>(cnt8, bsum, off8);
  hipMemcpyAsync(cursor8, off8, sizeof(int) * TOT8, hipMemcpyDeviceToDevice, stream);
  k_fill8<<<(tot + 255) / 256, 256, 0, stream>>>(ei, cursor8, csr8, E, N);

  // ---- skip projection (fp32 out) ----
  int gblocks = (N + 31) / 32;
  gemm128<<<gblocks, 256, 0, stream>>>(x, skip_W, skip_b, nullptr, nullptr,
                                       skip, nullptr, nullptr, nullptr, N);

  // ---- layers ----
  for (int l = 0; l < NLAYER; ++l) {
    const float* input = (l == 0) ? x : hcur;
    const float* resid = (l == 0) ? skip : hcur;
    gemm128<<<gblocks, 256, 0, stream>>>(input, Ws + (size_t)l * HID * HID, nullptr,
                                         a_src + l * HID, a_dst + l * HID,
                                         nullptr, hW, es, ed, N);
    edge_agg<<<(N + 3) / 4, 256, 0, stream>>>(hW, es, ed, off8, cnt8, csr8,
                                   gat_b + l * HID, ln_g + l * HID, ln_b + l * HID,
                                   resid, hcur, (l < NLAYER - 1) ? 1 : 0, N);
  }

  // ---- pooling + MLP ----
  hipMemsetAsync(zbeg, 0, zlen, stream);
  k_pool<<<(N + 63) / 64, 128, 0, stream>>>(hcur, batch, gsum, gmax, gcnt, N);
  k_mlp<<<NGR, 128, 0, stream>>>(gsum, gmax, gcnt, W1, b1, W2, b2, W3, b3, out);
}